// Round 1
// baseline (1984.125 us; speedup 1.0000x reference)
//
#include <hip/hip_runtime.h>
#include <math.h>

#define NB   256
#define NPG  2048
#define DD   128
#define DEGC 16
#define NTOT (NB * NPG)      // 524288 nodes
#define ETOT (NTOT * DEGC)   // 8388608 edges
#define KK   (NPG / 2)       // 1024 kept per graph
#define EPG  (NPG * DEGC)    // 32768 edges per graph

// ---------------- K1: h = x @ W  (half-wave per node, float4) ----------------
__global__ __launch_bounds__(256) void k_h(const float* __restrict__ x,
                                           const float* __restrict__ W,
                                           float* __restrict__ h) {
    int lane = threadIdx.x & 63;
    int wv   = threadIdx.x >> 6;
    int half = lane >> 5;
    int sub  = lane & 31;
    int node = blockIdx.x * 8 + wv * 2 + half;
    const float4* x4 = (const float4*)x;
    const float4* W4 = (const float4*)W;
    float4 xv = x4[(size_t)node * 32 + sub];
    float4 wv4 = W4[sub];
    float p = xv.x * wv4.x + xv.y * wv4.y + xv.z * wv4.z + xv.w * wv4.w;
    #pragma unroll
    for (int off = 16; off >= 1; off >>= 1) p += __shfl_xor(p, off, 64);
    if (sub == 0) h[node] = p;
}

// ---------------- K3: in-degree counts ----------------
__global__ __launch_bounds__(256) void k_count(const int* __restrict__ dst,
                                               int* __restrict__ cnt) {
    int e = blockIdx.x * 256 + threadIdx.x;
    atomicAdd(&cnt[dst[e]], 1);
}

// ---------------- K4: per-graph exclusive scan of counts -> ptr, cursor ------
__global__ __launch_bounds__(1024) void k_scan(const int* __restrict__ cnt,
                                               int* __restrict__ ptr,
                                               int* __restrict__ cursor) {
    int b = blockIdx.x, t = threadIdx.x;
    __shared__ int sums[1024];
    int n0 = b * NPG + 2 * t;
    int c0 = cnt[n0], c1 = cnt[n0 + 1];
    sums[t] = c0 + c1;
    __syncthreads();
    for (int off = 1; off < 1024; off <<= 1) {
        int v = (t >= off) ? sums[t - off] : 0;
        __syncthreads();
        sums[t] += v;
        __syncthreads();
    }
    int excl = (t > 0) ? sums[t - 1] : 0;
    int base = b * EPG;
    int p0 = base + excl;
    int p1 = p0 + c0;
    ptr[n0] = p0;     ptr[n0 + 1] = p1;
    cursor[n0] = p0;  cursor[n0 + 1] = p1;
}

// ---------------- K5: scatter edge ids into per-dst buckets ----------------
__global__ __launch_bounds__(256) void k_scatter(const int* __restrict__ dst,
                                                 int* __restrict__ cursor,
                                                 int* __restrict__ elist) {
    int e = blockIdx.x * 256 + threadIdx.x;
    int pos = atomicAdd(&cursor[dst[e]], 1);
    elist[pos] = e;
}

// ---- K6: sort each node's edge list asc (np.add.at order), deg, inv_sqrt ----
__global__ __launch_bounds__(256) void k_deg(const int* __restrict__ ptr,
                                             const int* __restrict__ cnt,
                                             int* __restrict__ elist,
                                             const float* __restrict__ w,
                                             float* __restrict__ is_arr) {
    int n = blockIdx.x * 256 + threadIdx.x;
    if (n >= NTOT) return;
    int beg = ptr[n], k = cnt[n];
    // insertion sort ascending (in place, segment is private to this thread)
    for (int i = 1; i < k; i++) {
        int v = elist[beg + i];
        int j = i - 1;
        while (j >= 0) {
            int u = elist[beg + j];
            if (u > v) { elist[beg + j + 1] = u; j--; } else break;
        }
        elist[beg + j + 1] = v;
    }
    float s = 0.0f;
    for (int i = 0; i < k; i++) s += w[elist[beg + i]];
    float deg = s + 1.0f;                 // matches ref: segment_sum(...) + 1.0
    is_arr[n] = 1.0f / sqrtf(deg);        // matches 1/np.sqrt in f32
}

// ---------------- K7: score (sequential, edge-id order, f32) ----------------
__global__ __launch_bounds__(256) void k_score(const int* __restrict__ ptr,
                                               const int* __restrict__ cnt,
                                               const int* __restrict__ elist,
                                               const int* __restrict__ src,
                                               const float* __restrict__ w,
                                               const float* __restrict__ h,
                                               const float* __restrict__ is_arr,
                                               float* __restrict__ score) {
    int n = blockIdx.x * 256 + threadIdx.x;
    if (n >= NTOT) return;
    int beg = ptr[n], k = cnt[n];
    float isd = is_arr[n];
    float s = 0.0f;
    for (int i = 0; i < k; i++) {
        int e = elist[beg + i];
        int sg = src[e];
        float v = ((w[e] * is_arr[sg]) * isd) * h[sg];  // ref rounding order
        s += v;
    }
    float isn = is_arr[n];
    s = s + h[n] * (isn * isn);           // self-loop term, ref rounding order
    score[n] = s;
}

// ------- K8: per-graph bitonic top-k (desc score, asc index ties) -----------
__global__ __launch_bounds__(1024) void k_topk(const float* __restrict__ score,
                                               int* __restrict__ topk,
                                               int* __restrict__ new_id,
                                               float* __restrict__ pngi) {
    int b = blockIdx.x, t = threadIdx.x;
    __shared__ unsigned long long key[NPG];
    for (int i = t; i < NPG; i += 1024) {
        float s = score[b * NPG + i];
        unsigned int u = __float_as_uint(s);
        u = (u & 0x80000000u) ? ~u : (u | 0x80000000u);  // ascending-order map
        unsigned int ks = ~u;                            // descending primary
        key[i] = ((unsigned long long)ks << 32) | (unsigned int)i;
    }
    __syncthreads();
    for (int k = 2; k <= NPG; k <<= 1) {
        for (int j = k >> 1; j > 0; j >>= 1) {
            int i = ((t & ~(j - 1)) << 1) | (t & (j - 1));
            int p = i | j;
            bool up = ((i & k) == 0);
            unsigned long long a = key[i], c = key[p];
            if ((a > c) == up) { key[i] = c; key[p] = a; }
            __syncthreads();
        }
    }
    // first KK keys = kept nodes in rank order
    int local = (int)(key[t] & 0xFFFFFFFFu);
    int node = b * NPG + local;
    int j = b * KK + t;
    topk[j] = node;
    new_id[node] = j;
    pngi[j] = (float)b;
}

// ---------------- K9: pooled_x = x[node] * tanh(score[node]) ----------------
__global__ __launch_bounds__(256) void k_gather(const float* __restrict__ x,
                                                const float* __restrict__ score,
                                                const int* __restrict__ topk,
                                                float* __restrict__ out) {
    int q = blockIdx.x * 256 + threadIdx.x;   // float4 index
    int row = q >> 5, c = q & 31;
    int node = topk[row];
    float g = tanhf(score[node]);
    const float4* x4 = (const float4*)x;
    float4 v = x4[(size_t)node * 32 + c];
    float4 o;
    o.x = v.x * g; o.y = v.y * g; o.z = v.z * g; o.w = v.w * g;
    ((float4*)out)[q] = o;
}

// ---------------- K10: edge remap + weight mask ----------------
__global__ __launch_bounds__(256) void k_edges(const int* __restrict__ src,
                                               const int* __restrict__ dst,
                                               const float* __restrict__ w,
                                               const int* __restrict__ new_id,
                                               float* __restrict__ pei0,
                                               float* __restrict__ pei1,
                                               float* __restrict__ pew) {
    int e = blockIdx.x * 256 + threadIdx.x;
    int s = src[e], d = dst[e];
    int ns = new_id[s], nd = new_id[d];
    bool m = (ns >= 0) && (nd >= 0);
    pei0[e] = m ? (float)ns : -1.0f;
    pei1[e] = m ? (float)nd : -1.0f;
    pew[e]  = m ? w[e] : 0.0f;
}

extern "C" void kernel_launch(void* const* d_in, const int* in_sizes, int n_in,
                              void* d_out, int out_size, void* d_ws, size_t ws_size,
                              hipStream_t stream) {
    const float* x   = (const float*)d_in[0];
    const int*   ei  = (const int*)d_in[1];
    const float* w   = (const float*)d_in[2];
    // d_in[3] = node_graph_index (unused: graphs are uniform)
    const float* W   = (const float*)d_in[4];
    const int* src = ei;
    const int* dst = ei + ETOT;

    // workspace layout
    char* ws = (char*)d_ws;
    float* h      = (float*)(ws);                       // N floats
    float* is_arr = (float*)(ws + (size_t)NTOT * 4);    // N floats
    float* score  = (float*)(ws + (size_t)NTOT * 8);    // N floats
    int*   cnt    = (int*)  (ws + (size_t)NTOT * 12);   // N ints
    int*   ptr    = (int*)  (ws + (size_t)NTOT * 16);   // N ints
    int*   cursor = (int*)  (ws + (size_t)NTOT * 20);   // N ints
    int*   new_id = (int*)  (ws + (size_t)NTOT * 24);   // N ints
    int*   topk   = (int*)  (ws + (size_t)NTOT * 28);   // B*K ints
    int*   elist  = (int*)  (ws + (size_t)NTOT * 28 + (size_t)NB * KK * 4); // E ints

    // output layout (all float32)
    float* out_px   = (float*)d_out;                       // [B*K, D]
    float* out_pei0 = out_px + (size_t)NB * KK * DD;       // [E]
    float* out_pei1 = out_pei0 + ETOT;                     // [E]
    float* out_pew  = out_pei1 + ETOT;                     // [E]
    float* out_pngi = out_pew + ETOT;                      // [B*K]

    hipMemsetAsync(cnt, 0, (size_t)NTOT * 4, stream);
    hipMemsetAsync(new_id, 0xFF, (size_t)NTOT * 4, stream);  // -1

    k_h<<<NTOT / 8, 256, 0, stream>>>(x, W, h);
    k_count<<<ETOT / 256, 256, 0, stream>>>(dst, cnt);
    k_scan<<<NB, 1024, 0, stream>>>(cnt, ptr, cursor);
    k_scatter<<<ETOT / 256, 256, 0, stream>>>(dst, cursor, elist);
    k_deg<<<(NTOT + 255) / 256, 256, 0, stream>>>(ptr, cnt, elist, w, is_arr);
    k_score<<<(NTOT + 255) / 256, 256, 0, stream>>>(ptr, cnt, elist, src, w, h, is_arr, score);
    k_topk<<<NB, 1024, 0, stream>>>(score, topk, new_id, out_pngi);
    k_gather<<<(NB * KK * DD / 4) / 256, 256, 0, stream>>>(x, score, topk, out_px);
    k_edges<<<ETOT / 256, 256, 0, stream>>>(src, dst, w, new_id, out_pei0, out_pei1, out_pew);
}

// Round 2
// 1192.002 us; speedup vs baseline: 1.6645x; 1.6645x over previous
//
#include <hip/hip_runtime.h>
#include <math.h>

#define NB   256
#define NPG  2048
#define DD   128
#define DEGC 16
#define NTOT (NB * NPG)      // 524288 nodes
#define ETOT (NTOT * DEGC)   // 8388608 edges
#define KK   (NPG / 2)       // 1024 kept per graph
#define EPG  (NPG * DEGC)    // 32768 edges per graph
#define MAXK 48              // per-node in-degree cap for LDS path (P(exceed) ~ 1e-9/node)
#define ROWW 49              // 49 coprime with 32 banks -> conflict-free row bases

// ---------------- K1: h = x @ W  (half-wave per node, float4) ----------------
__global__ __launch_bounds__(256) void k_h(const float* __restrict__ x,
                                           const float* __restrict__ W,
                                           float* __restrict__ h) {
    int lane = threadIdx.x & 63;
    int wv   = threadIdx.x >> 6;
    int half = lane >> 5;
    int sub  = lane & 31;
    int node = blockIdx.x * 8 + wv * 2 + half;
    const float4* x4 = (const float4*)x;
    const float4* W4 = (const float4*)W;
    float4 xv = x4[(size_t)node * 32 + sub];
    float4 wv4 = W4[sub];
    float p = xv.x * wv4.x + xv.y * wv4.y + xv.z * wv4.z + xv.w * wv4.w;
    #pragma unroll
    for (int off = 16; off >= 1; off >>= 1) p += __shfl_xor(p, off, 64);
    if (sub == 0) h[node] = p;
}

// ---- K2: per-graph count + scan + scatter, one block per graph, LDS ----
__global__ __launch_bounds__(1024) void k_build(const int* __restrict__ dst,
                                                int* __restrict__ ptr_g,
                                                int* __restrict__ cnt_g,
                                                int* __restrict__ elist) {
    int b = blockIdx.x, t = threadIdx.x;
    __shared__ int cnt[NPG];    // 8 KB
    __shared__ int cur[NPG];    // 8 KB
    __shared__ int sums[1024];  // 4 KB
    const int* dslab = dst + (size_t)b * EPG;
    // phase 1: zero + count
    cnt[t] = 0; cnt[t + 1024] = 0;
    __syncthreads();
    #pragma unroll
    for (int i = 0; i < EPG / 1024; i++) {
        int d = dslab[i * 1024 + t] - b * NPG;
        atomicAdd(&cnt[d], 1);
    }
    __syncthreads();
    // phase 2: exclusive scan over 2048 counters (2 per thread)
    int c0 = cnt[2 * t], c1 = cnt[2 * t + 1];
    sums[t] = c0 + c1;
    __syncthreads();
    for (int off = 1; off < 1024; off <<= 1) {
        int v = (t >= off) ? sums[t - off] : 0;
        __syncthreads();
        sums[t] += v;
        __syncthreads();
    }
    int excl = (t > 0) ? sums[t - 1] : 0;
    int p0 = excl;          // local offsets within graph slab
    int p1 = p0 + c0;
    cur[2 * t] = p0; cur[2 * t + 1] = p1;
    int base = b * EPG;
    ptr_g[b * NPG + 2 * t]     = base + p0;
    ptr_g[b * NPG + 2 * t + 1] = base + p1;
    cnt_g[b * NPG + 2 * t]     = c0;
    cnt_g[b * NPG + 2 * t + 1] = c1;
    __syncthreads();
    // phase 3: scatter edge ids (order arbitrary; k_deg sorts each bucket)
    #pragma unroll
    for (int i = 0; i < EPG / 1024; i++) {
        int e = i * 1024 + t;
        int d = dslab[e] - b * NPG;
        int pos = atomicAdd(&cur[d], 1);
        elist[base + pos] = base + e;
    }
}

// ---- K3: sort each node's edge list asc in LDS (np.add.at order), deg ----
__global__ __launch_bounds__(256) void k_deg(const int* __restrict__ ptr,
                                             const int* __restrict__ cnt,
                                             int* __restrict__ elist,
                                             const float* __restrict__ w,
                                             float* __restrict__ is_arr) {
    __shared__ int buf[256 * ROWW];   // ~50 KB
    int n = blockIdx.x * 256 + threadIdx.x;
    int* row = &buf[threadIdx.x * ROWW];
    int beg = ptr[n], k = cnt[n];
    float s = 0.0f;
    if (k <= MAXK) {
        for (int i = 0; i < k; i++) row[i] = elist[beg + i];
        for (int i = 1; i < k; i++) {
            int v = row[i];
            int j = i - 1;
            while (j >= 0) {
                int u = row[j];
                if (u > v) { row[j + 1] = u; j--; } else break;
            }
            row[j + 1] = v;
        }
        for (int i = 0; i < k; i++) elist[beg + i] = row[i];
        for (int i = 0; i < k; i++) s += w[row[i]];
    } else {
        // rare fallback: sort in place in global memory
        for (int i = 1; i < k; i++) {
            int v = elist[beg + i];
            int j = i - 1;
            while (j >= 0) {
                int u = elist[beg + j];
                if (u > v) { elist[beg + j + 1] = u; j--; } else break;
            }
            elist[beg + j + 1] = v;
        }
        for (int i = 0; i < k; i++) s += w[elist[beg + i]];
    }
    float deg = s + 1.0f;                 // matches ref: segment_sum(...) + 1.0
    is_arr[n] = 1.0f / sqrtf(deg);
}

// ---------------- K4: score (sequential, edge-id order, f32) ----------------
__global__ __launch_bounds__(256) void k_score(const int* __restrict__ ptr,
                                               const int* __restrict__ cnt,
                                               const int* __restrict__ elist,
                                               const int* __restrict__ src,
                                               const float* __restrict__ w,
                                               const float* __restrict__ h,
                                               const float* __restrict__ is_arr,
                                               float* __restrict__ score) {
    int n = blockIdx.x * 256 + threadIdx.x;
    int beg = ptr[n], k = cnt[n];
    float isd = is_arr[n];
    float s = 0.0f;
    for (int i = 0; i < k; i++) {
        int e = elist[beg + i];
        int sg = src[e];
        float v = ((w[e] * is_arr[sg]) * isd) * h[sg];  // ref rounding order
        s += v;
    }
    s = s + h[n] * (isd * isd);           // self-loop term, ref rounding order
    score[n] = s;
}

// ------- K5: per-graph bitonic top-k (desc score, asc index ties) -----------
__global__ __launch_bounds__(1024) void k_topk(const float* __restrict__ score,
                                               int* __restrict__ topk,
                                               int* __restrict__ new_id,
                                               float* __restrict__ pngi) {
    int b = blockIdx.x, t = threadIdx.x;
    __shared__ unsigned long long key[NPG];
    for (int i = t; i < NPG; i += 1024) {
        float s = score[b * NPG + i];
        unsigned int u = __float_as_uint(s);
        u = (u & 0x80000000u) ? ~u : (u | 0x80000000u);  // ascending-order map
        unsigned int ks = ~u;                            // descending primary
        key[i] = ((unsigned long long)ks << 32) | (unsigned int)i;
    }
    __syncthreads();
    for (int k = 2; k <= NPG; k <<= 1) {
        for (int j = k >> 1; j > 0; j >>= 1) {
            int i = ((t & ~(j - 1)) << 1) | (t & (j - 1));
            int p = i | j;
            bool up = ((i & k) == 0);
            unsigned long long a = key[i], c = key[p];
            if ((a > c) == up) { key[i] = c; key[p] = a; }
            __syncthreads();
        }
    }
    int local = (int)(key[t] & 0xFFFFFFFFu);
    int node = b * NPG + local;
    int j = b * KK + t;
    topk[j] = node;
    new_id[node] = j;
    pngi[j] = (float)b;
}

// ---------------- K6: pooled_x = x[node] * tanh(score[node]) ----------------
__global__ __launch_bounds__(256) void k_gather(const float* __restrict__ x,
                                                const float* __restrict__ score,
                                                const int* __restrict__ topk,
                                                float* __restrict__ out) {
    int q = blockIdx.x * 256 + threadIdx.x;   // float4 index
    int row = q >> 5, c = q & 31;
    int node = topk[row];
    float g = tanhf(score[node]);
    const float4* x4 = (const float4*)x;
    float4 v = x4[(size_t)node * 32 + c];
    float4 o;
    o.x = v.x * g; o.y = v.y * g; o.z = v.z * g; o.w = v.w * g;
    ((float4*)out)[q] = o;
}

// ---------------- K7: edge remap + weight mask ----------------
__global__ __launch_bounds__(256) void k_edges(const int* __restrict__ src,
                                               const int* __restrict__ dst,
                                               const float* __restrict__ w,
                                               const int* __restrict__ new_id,
                                               float* __restrict__ pei0,
                                               float* __restrict__ pei1,
                                               float* __restrict__ pew) {
    int e = blockIdx.x * 256 + threadIdx.x;
    int s = src[e], d = dst[e];
    int ns = new_id[s], nd = new_id[d];
    bool m = (ns >= 0) && (nd >= 0);
    pei0[e] = m ? (float)ns : -1.0f;
    pei1[e] = m ? (float)nd : -1.0f;
    pew[e]  = m ? w[e] : 0.0f;
}

extern "C" void kernel_launch(void* const* d_in, const int* in_sizes, int n_in,
                              void* d_out, int out_size, void* d_ws, size_t ws_size,
                              hipStream_t stream) {
    const float* x   = (const float*)d_in[0];
    const int*   ei  = (const int*)d_in[1];
    const float* w   = (const float*)d_in[2];
    // d_in[3] = node_graph_index (unused: graphs are uniform)
    const float* W   = (const float*)d_in[4];
    const int* src = ei;
    const int* dst = ei + ETOT;

    // workspace layout
    char* ws = (char*)d_ws;
    float* h      = (float*)(ws);                       // N floats
    float* is_arr = (float*)(ws + (size_t)NTOT * 4);    // N floats
    float* score  = (float*)(ws + (size_t)NTOT * 8);    // N floats
    int*   cnt    = (int*)  (ws + (size_t)NTOT * 12);   // N ints
    int*   ptr    = (int*)  (ws + (size_t)NTOT * 16);   // N ints
    int*   new_id = (int*)  (ws + (size_t)NTOT * 20);   // N ints
    int*   topk   = (int*)  (ws + (size_t)NTOT * 24);   // B*K ints
    int*   elist  = (int*)  (ws + (size_t)NTOT * 24 + (size_t)NB * KK * 4); // E ints

    // output layout (all float32)
    float* out_px   = (float*)d_out;                       // [B*K, D]
    float* out_pei0 = out_px + (size_t)NB * KK * DD;       // [E]
    float* out_pei1 = out_pei0 + ETOT;                     // [E]
    float* out_pew  = out_pei1 + ETOT;                     // [E]
    float* out_pngi = out_pew + ETOT;                      // [B*K]

    hipMemsetAsync(new_id, 0xFF, (size_t)NTOT * 4, stream);  // -1

    k_h<<<NTOT / 8, 256, 0, stream>>>(x, W, h);
    k_build<<<NB, 1024, 0, stream>>>(dst, ptr, cnt, elist);
    k_deg<<<NTOT / 256, 256, 0, stream>>>(ptr, cnt, elist, w, is_arr);
    k_score<<<NTOT / 256, 256, 0, stream>>>(ptr, cnt, elist, src, w, h, is_arr, score);
    k_topk<<<NB, 1024, 0, stream>>>(score, topk, new_id, out_pngi);
    k_gather<<<(NB * KK * DD / 4) / 256, 256, 0, stream>>>(x, score, topk, out_px);
    k_edges<<<ETOT / 256, 256, 0, stream>>>(src, dst, w, new_id, out_pei0, out_pei1, out_pew);
}